// Round 1
// baseline (3169.159 us; speedup 1.0000x reference)
//
#include <hip/hip_runtime.h>
#include <hip/hip_bf16.h>

// DRew-GIN: N=50000 nodes, E=800000 edges, D=128, L=3, NU=1.
// Layer t: out = (1+eps)*relu(xt@Ws[t]+bs) + sum_k relu(segsum(xs[t-k+1][src] * (attr==k)) @ Wk[t,k-1] + bk)
//          xs[t+1] = xt + relu(out)

#define NODES 50000
#define EDGES 800000
#define DIM   128
#define ND    ((long)NODES * DIM)   // 6.4M elements

typedef __attribute__((ext_vector_type(8))) short  bf16x8;  // 8 bf16 in 4 VGPRs
typedef __attribute__((ext_vector_type(4))) float  f32x4;

// ---------------------------------------------------------------------------
// Convert Ws (3 mats) + Wk (9 mats) f32 [k][n] -> bf16 transposed [n][k].
// WT holds 12 matrices of 128x128 bf16: m=0..2 -> Ws[t]; m=3+t*3+(k-1) -> Wk[t][k-1].
__global__ __launch_bounds__(256) void convw_kernel(
    const float* __restrict__ Ws, const float* __restrict__ Wk,
    __hip_bfloat16* __restrict__ WT) {
  int m = blockIdx.x;                                            // 0..11
  const float* src = (m < 3) ? (Ws + (long)m * 16384) : (Wk + (long)(m - 3) * 16384);
  __hip_bfloat16* dst = WT + (long)m * 16384;
  for (int idx = threadIdx.x; idx < 16384; idx += 256) {
    int k = idx >> 7, n = idx & 127;
    dst[n * 128 + k] = __float2bfloat16(src[idx]);
  }
}

// ---------------------------------------------------------------------------
// GEMM: dst[M x 128] (op)= epilogue(A[M x 128] @ B[128 x 128])
// A: f32 row-major (converted to bf16 in LDS staging).
// Bt: bf16, transposed [n][k].
// mode 0: dst = (1+*epsp) * relu(acc + bias)
// mode 1: dst += relu(acc + bias)
#define LDS_STRIDE 136   // 128 + 8 bf16 pad -> 272B row stride, 2-way bank alias only
__global__ __launch_bounds__(256) void gemm_kernel(
    const float* __restrict__ A,
    const __hip_bfloat16* __restrict__ Bt,
    const float* __restrict__ bias,
    const float* __restrict__ epsp,
    float* __restrict__ dst,
    int M, int accumulate) {
  __shared__ __hip_bfloat16 b_lds[128 * LDS_STRIDE];  // 34816 B
  __shared__ __hip_bfloat16 a_lds[64 * LDS_STRIDE];   // 17408 B

  int tid = threadIdx.x;

  // Stage B: 128x128 bf16 = 2048 float4 chunks, 8 per thread.
  const float4* bsrc = (const float4*)Bt;
  for (int i = 0; i < 8; ++i) {
    int idx = tid + 256 * i;            // 0..2047
    int n = idx >> 4, k8 = idx & 15;    // 16 chunks of 8 bf16 per row
    float4 v = bsrc[idx];
    *(float4*)(b_lds + n * LDS_STRIDE + k8 * 8) = v;  // byte off 272n+16k8, 16-aligned
  }

  // Stage A: 64 rows x 128 f32 -> bf16. 2048 float4 chunks, 8 per thread.
  long row0 = (long)blockIdx.x * 64;
  for (int i = 0; i < 8; ++i) {
    int c = tid + 256 * i;              // 0..2047
    int r = c >> 5, c4 = c & 31;        // 32 float4 per row
    long grow = row0 + r;
    float4 v = make_float4(0.f, 0.f, 0.f, 0.f);
    if (grow < M) v = *(const float4*)(A + grow * DIM + c4 * 4);
    union { __hip_bfloat16 h[4]; uint2 u; } pk;
    pk.h[0] = __float2bfloat16(v.x);
    pk.h[1] = __float2bfloat16(v.y);
    pk.h[2] = __float2bfloat16(v.z);
    pk.h[3] = __float2bfloat16(v.w);
    *(uint2*)(a_lds + r * LDS_STRIDE + c4 * 4) = pk.u;  // byte off 272r+8c4, 8-aligned
  }
  __syncthreads();

  int wave = tid >> 6, lane = tid & 63;
  int l15 = lane & 15, q = lane >> 4;

  f32x4 acc[8] = {};  // 8 n-tiles of 16 cols; wave covers 16 rows x 128 cols
  for (int k0 = 0; k0 < 128; k0 += 32) {
    bf16x8 af = *(const bf16x8*)(a_lds + (wave * 16 + l15) * LDS_STRIDE + k0 + 8 * q);
#pragma unroll
    for (int j = 0; j < 8; ++j) {
      bf16x8 bfr = *(const bf16x8*)(b_lds + (16 * j + l15) * LDS_STRIDE + k0 + 8 * q);
      acc[j] = __builtin_amdgcn_mfma_f32_16x16x32_bf16(af, bfr, acc[j], 0, 0, 0);
    }
  }

  // Epilogue. D mapping: col = lane&15 (+16j), row = q*4 + r.
  float scale = accumulate ? 1.0f : (1.0f + *epsp);
  long rbase = row0 + wave * 16 + q * 4;
#pragma unroll
  for (int j = 0; j < 8; ++j) {
    int col = 16 * j + l15;
    float b = bias[col];
#pragma unroll
    for (int r = 0; r < 4; ++r) {
      long grow = rbase + r;
      if (grow < M) {
        float v = fmaxf(acc[j][r] + b, 0.0f);
        if (accumulate) dst[grow * DIM + col] += v;
        else            dst[grow * DIM + col]  = scale * v;
      }
    }
  }
}

// ---------------------------------------------------------------------------
// Scatter: for each edge with attr==k: agg[dst] += xsrc[src]  (128 f32/row).
// 32 lanes per edge, float4 per lane.
__global__ __launch_bounds__(256) void scatter_kernel(
    const float* __restrict__ xsrc,
    const int* __restrict__ ei,      // [2][E]
    const int* __restrict__ attr,    // [E]
    int k, float* __restrict__ agg, int E) {
  int sub  = threadIdx.x >> 5;   // 0..7
  int lane = threadIdx.x & 31;
  long e = (long)blockIdx.x * 8 + sub;
  if (e >= E) return;
  if (attr[e] != k) return;
  int s = ei[e];
  int d = ei[(long)E + e];
  float4 v = *(const float4*)(xsrc + (long)s * DIM + lane * 4);
  float* drow = agg + (long)d * DIM + lane * 4;
  unsafeAtomicAdd(drow + 0, v.x);
  unsafeAtomicAdd(drow + 1, v.y);
  unsafeAtomicAdd(drow + 2, v.z);
  unsafeAtomicAdd(drow + 3, v.w);
}

// ---------------------------------------------------------------------------
// xs[t+1] = xt + relu(out_acc)
__global__ __launch_bounds__(256) void residual_kernel(
    const float4* __restrict__ xt, const float4* __restrict__ oa,
    float4* __restrict__ xn, long n4) {
  long i = (long)blockIdx.x * 256 + threadIdx.x;
  if (i >= n4) return;
  float4 a = xt[i], b = oa[i];
  xn[i] = make_float4(a.x + fmaxf(b.x, 0.f), a.y + fmaxf(b.y, 0.f),
                      a.z + fmaxf(b.z, 0.f), a.w + fmaxf(b.w, 0.f));
}

// ---------------------------------------------------------------------------
extern "C" void kernel_launch(void* const* d_in, const int* in_sizes, int n_in,
                              void* d_out, int out_size, void* d_ws, size_t ws_size,
                              hipStream_t stream) {
  const float* x    = (const float*)d_in[0];
  const int*   ei   = (const int*)d_in[1];
  const int*   attr = (const int*)d_in[2];
  const float* Ws   = (const float*)d_in[3];
  const float* bs   = (const float*)d_in[4];
  const float* Wk   = (const float*)d_in[5];
  const float* bk   = (const float*)d_in[6];
  const float* eps  = (const float*)d_in[7];
  float* out = (float*)d_out;

  char* ws = (char*)d_ws;
  float* xs1 = (float*)(ws);
  float* xs2 = (float*)(ws + ND * 4);
  float* oac = (float*)(ws + 2 * ND * 4);
  float* agg = (float*)(ws + 3 * ND * 4);
  __hip_bfloat16* WT = (__hip_bfloat16*)(ws + 4 * ND * 4);  // 12 * 16384 bf16

  const float* xsr[4] = {x, xs1, xs2, out};
  float*       xsw[4] = {nullptr, xs1, xs2, out};

  hipLaunchKernelGGL(convw_kernel, dim3(12), dim3(256), 0, stream, Ws, Wk, WT);

  int ggrid = (NODES + 63) / 64;      // 782
  int sgrid = (EDGES + 7) / 8;        // 100000
  int rgrid = (int)(ND / 4 / 256);    // 6250

  for (int t = 0; t < 3; ++t) {
    const float* xt = xsr[t];
    // out_acc = (1+eps[t]) * relu(xt @ Ws[t] + bs[t])
    hipLaunchKernelGGL(gemm_kernel, dim3(ggrid), dim3(256), 0, stream,
                       xt, WT + (long)t * 16384, bs + t * 128, eps + t, oac, NODES, 0);
    for (int k = 1; k <= t + 1; ++k) {
      hipMemsetAsync(agg, 0, ND * 4, stream);
      const float* xsrc = xsr[t - (k - 1)];  // delay = k-1 (NU=1)
      hipLaunchKernelGGL(scatter_kernel, dim3(sgrid), dim3(256), 0, stream,
                         xsrc, ei, attr, k, agg, EDGES);
      // out_acc += relu(agg @ Wk[t][k-1] + bk[t][k-1])
      hipLaunchKernelGGL(gemm_kernel, dim3(ggrid), dim3(256), 0, stream,
                         agg, WT + (long)(3 + t * 3 + (k - 1)) * 16384,
                         bk + (t * 3 + (k - 1)) * 128, (const float*)nullptr,
                         oac, NODES, 1);
    }
    hipLaunchKernelGGL(residual_kernel, dim3(rgrid), dim3(256), 0, stream,
                       (const float4*)xt, (const float4*)oac, (float4*)xsw[t + 1], ND / 4);
  }
}

// Round 2
// 666.660 us; speedup vs baseline: 4.7538x; 4.7538x over previous
//
#include <hip/hip_runtime.h>
#include <hip/hip_bf16.h>

// DRew-GIN: N=50000 nodes, E=800000 edges, D=128, L=3, NU=1.
// R2: replace atomic scatter with CSR-by-(k,dst) build + register gather.

#define NODES 50000
#define EDGES 800000
#define DIM   128
#define ND    ((long)NODES * DIM)   // 6.4M elements
#define NB3   (3 * NODES)          // 150000 buckets: (k-1)*N + dst

typedef __attribute__((ext_vector_type(8))) short  bf16x8;
typedef __attribute__((ext_vector_type(4))) float  f32x4;

// ---------------------------------------------------------------------------
// Convert Ws (3 mats) + Wk (9 mats) f32 [k][n] -> bf16 transposed [n][k].
__global__ __launch_bounds__(256) void convw_kernel(
    const float* __restrict__ Ws, const float* __restrict__ Wk,
    __hip_bfloat16* __restrict__ WT) {
  int m = blockIdx.x;  // 0..11
  const float* src = (m < 3) ? (Ws + (long)m * 16384) : (Wk + (long)(m - 3) * 16384);
  __hip_bfloat16* dst = WT + (long)m * 16384;
  for (int idx = threadIdx.x; idx < 16384; idx += 256) {
    int k = idx >> 7, n = idx & 127;
    dst[n * 128 + k] = __float2bfloat16(src[idx]);
  }
}

// ---------------------------------------------------------------------------
// CSR build, phase 1: histogram into counts[(attr-1)*N + dst].
__global__ __launch_bounds__(256) void hist_kernel(
    const int* __restrict__ ei, const int* __restrict__ attr,
    int* __restrict__ counts, int E) {
  int e = blockIdx.x * 256 + threadIdx.x;
  if (e >= E) return;
  int k = attr[e];            // 1..3
  int d = ei[E + e];
  atomicAdd(&counts[(k - 1) * NODES + d], 1);
}

// Phase 2a: per-256-chunk exclusive scan; chunk totals -> blocksums.
__global__ __launch_bounds__(256) void scan_a_kernel(
    const int* __restrict__ counts, int* __restrict__ partial,
    int* __restrict__ blocksums, int n) {
  __shared__ int tmp[256];
  int gid = blockIdx.x * 256 + threadIdx.x;
  int v = (gid < n) ? counts[gid] : 0;
  tmp[threadIdx.x] = v;
  __syncthreads();
  for (int off = 1; off < 256; off <<= 1) {
    int t = (threadIdx.x >= off) ? tmp[threadIdx.x - off] : 0;
    __syncthreads();
    tmp[threadIdx.x] += t;
    __syncthreads();
  }
  if (gid < n) partial[gid] = tmp[threadIdx.x] - v;   // exclusive
  if (threadIdx.x == 255) blocksums[blockIdx.x] = tmp[255];
}

// Phase 2b: single-block exclusive scan of blocksums (with running carry).
__global__ __launch_bounds__(256) void scan_b_kernel(int* __restrict__ bs, int nb) {
  __shared__ int tmp[256];
  __shared__ int carry;
  if (threadIdx.x == 0) carry = 0;
  __syncthreads();
  for (int base = 0; base < nb; base += 256) {
    int gid = base + threadIdx.x;
    int v = (gid < nb) ? bs[gid] : 0;
    tmp[threadIdx.x] = v;
    __syncthreads();
    for (int off = 1; off < 256; off <<= 1) {
      int t = (threadIdx.x >= off) ? tmp[threadIdx.x - off] : 0;
      __syncthreads();
      tmp[threadIdx.x] += t;
      __syncthreads();
    }
    if (gid < nb) bs[gid] = tmp[threadIdx.x] - v + carry;
    __syncthreads();
    if (threadIdx.x == 0) carry += tmp[255];
    __syncthreads();
  }
}

// Phase 2c: combine; rowptr = cursor = global exclusive scan; rowptr[n] = E.
__global__ __launch_bounds__(256) void scan_c_kernel(
    int* __restrict__ rowptr, int* __restrict__ cursor,
    const int* __restrict__ bs, int n) {
  int gid = blockIdx.x * 256 + threadIdx.x;
  if (gid >= n) return;
  int cnt = cursor[gid];                 // original count (read before overwrite)
  int val = rowptr[gid] + bs[blockIdx.x];
  rowptr[gid] = val;
  cursor[gid] = val;
  if (gid == n - 1) rowptr[n] = val + cnt;
}

// Phase 3: scatter src ids into sorted position.
__global__ __launch_bounds__(256) void fill_kernel(
    const int* __restrict__ ei, const int* __restrict__ attr,
    int* __restrict__ cursor, int* __restrict__ csr_src, int E) {
  int e = blockIdx.x * 256 + threadIdx.x;
  if (e >= E) return;
  int k = attr[e];
  int d = ei[E + e];
  int s = ei[e];
  int pos = atomicAdd(&cursor[(k - 1) * NODES + d], 1);
  csr_src[pos] = s;
}

// ---------------------------------------------------------------------------
// Gather: agg[d] = sum over incoming edges (bucket (k-1)*N+d) of xsrc[src].
// 32 lanes per node (float4/lane), 8 nodes per block. No atomics, no memset.
__global__ __launch_bounds__(256) void gather_kernel(
    const float* __restrict__ xsrc,
    const int* __restrict__ rowptr, const int* __restrict__ csr_src,
    int km1, float* __restrict__ agg) {
  int sub = threadIdx.x >> 5, lane = threadIdx.x & 31;
  int d = blockIdx.x * 8 + sub;
  if (d >= NODES) return;
  int b = km1 * NODES + d;
  int beg = rowptr[b], end = rowptr[b + 1];
  float4 acc = make_float4(0.f, 0.f, 0.f, 0.f);
  for (int i = beg; i < end; ++i) {
    int s = csr_src[i];
    float4 v = *(const float4*)(xsrc + (long)s * DIM + lane * 4);
    acc.x += v.x; acc.y += v.y; acc.z += v.z; acc.w += v.w;
  }
  *(float4*)(agg + (long)d * DIM + lane * 4) = acc;
}

// ---------------------------------------------------------------------------
// GEMM: dst[M x 128] (op)= epilogue(A[M x 128] @ B[128 x 128])
#define LDS_STRIDE 136
__global__ __launch_bounds__(256) void gemm_kernel(
    const float* __restrict__ A,
    const __hip_bfloat16* __restrict__ Bt,
    const float* __restrict__ bias,
    const float* __restrict__ epsp,
    float* __restrict__ dst,
    int M, int accumulate) {
  __shared__ __hip_bfloat16 b_lds[128 * LDS_STRIDE];
  __shared__ __hip_bfloat16 a_lds[64 * LDS_STRIDE];

  int tid = threadIdx.x;

  const float4* bsrc = (const float4*)Bt;
  for (int i = 0; i < 8; ++i) {
    int idx = tid + 256 * i;
    int n = idx >> 4, k8 = idx & 15;
    float4 v = bsrc[idx];
    *(float4*)(b_lds + n * LDS_STRIDE + k8 * 8) = v;
  }

  long row0 = (long)blockIdx.x * 64;
  for (int i = 0; i < 8; ++i) {
    int c = tid + 256 * i;
    int r = c >> 5, c4 = c & 31;
    long grow = row0 + r;
    float4 v = make_float4(0.f, 0.f, 0.f, 0.f);
    if (grow < M) v = *(const float4*)(A + grow * DIM + c4 * 4);
    union { __hip_bfloat16 h[4]; uint2 u; } pk;
    pk.h[0] = __float2bfloat16(v.x);
    pk.h[1] = __float2bfloat16(v.y);
    pk.h[2] = __float2bfloat16(v.z);
    pk.h[3] = __float2bfloat16(v.w);
    *(uint2*)(a_lds + r * LDS_STRIDE + c4 * 4) = pk.u;
  }
  __syncthreads();

  int wave = tid >> 6, lane = tid & 63;
  int l15 = lane & 15, q = lane >> 4;

  f32x4 acc[8] = {};
  for (int k0 = 0; k0 < 128; k0 += 32) {
    bf16x8 af = *(const bf16x8*)(a_lds + (wave * 16 + l15) * LDS_STRIDE + k0 + 8 * q);
#pragma unroll
    for (int j = 0; j < 8; ++j) {
      bf16x8 bfr = *(const bf16x8*)(b_lds + (16 * j + l15) * LDS_STRIDE + k0 + 8 * q);
      acc[j] = __builtin_amdgcn_mfma_f32_16x16x32_bf16(af, bfr, acc[j], 0, 0, 0);
    }
  }

  float scale = accumulate ? 1.0f : (1.0f + *epsp);
  long rbase = row0 + wave * 16 + q * 4;
#pragma unroll
  for (int j = 0; j < 8; ++j) {
    int col = 16 * j + l15;
    float b = bias[col];
#pragma unroll
    for (int r = 0; r < 4; ++r) {
      long grow = rbase + r;
      if (grow < M) {
        float v = fmaxf(acc[j][r] + b, 0.0f);
        if (accumulate) dst[grow * DIM + col] += v;
        else            dst[grow * DIM + col]  = scale * v;
      }
    }
  }
}

// ---------------------------------------------------------------------------
// xs[t+1] = xt + relu(out_acc)
__global__ __launch_bounds__(256) void residual_kernel(
    const float4* __restrict__ xt, const float4* __restrict__ oa,
    float4* __restrict__ xn, long n4) {
  long i = (long)blockIdx.x * 256 + threadIdx.x;
  if (i >= n4) return;
  float4 a = xt[i], b = oa[i];
  xn[i] = make_float4(a.x + fmaxf(b.x, 0.f), a.y + fmaxf(b.y, 0.f),
                      a.z + fmaxf(b.z, 0.f), a.w + fmaxf(b.w, 0.f));
}

// ---------------------------------------------------------------------------
extern "C" void kernel_launch(void* const* d_in, const int* in_sizes, int n_in,
                              void* d_out, int out_size, void* d_ws, size_t ws_size,
                              hipStream_t stream) {
  const float* x    = (const float*)d_in[0];
  const int*   ei   = (const int*)d_in[1];
  const int*   attr = (const int*)d_in[2];
  const float* Ws   = (const float*)d_in[3];
  const float* bs   = (const float*)d_in[4];
  const float* Wk   = (const float*)d_in[5];
  const float* bk   = (const float*)d_in[6];
  const float* eps  = (const float*)d_in[7];
  float* out = (float*)d_out;

  char* ws = (char*)d_ws;
  size_t off = 0;
  auto alloc = [&](size_t bytes) { char* p = ws + off; off += (bytes + 255) & ~(size_t)255; return p; };
  float* xs1 = (float*)alloc(ND * 4);
  float* xs2 = (float*)alloc(ND * 4);
  float* oac = (float*)alloc(ND * 4);
  float* agg = (float*)alloc(ND * 4);
  __hip_bfloat16* WT = (__hip_bfloat16*)alloc(12 * 16384 * 2);
  int* cursor    = (int*)alloc((size_t)NB3 * 4);
  int* rowptr    = (int*)alloc((size_t)(NB3 + 1) * 4);
  int* blocksums = (int*)alloc(1024 * 4);
  int* csr_src   = (int*)alloc((size_t)EDGES * 4);

  const float* xsr[4] = {x, xs1, xs2, out};
  float*       xsw[4] = {nullptr, xs1, xs2, out};

  // Weight conversion + CSR build (independent of layer loop).
  hipLaunchKernelGGL(convw_kernel, dim3(12), dim3(256), 0, stream, Ws, Wk, WT);
  hipMemsetAsync(cursor, 0, (size_t)NB3 * 4, stream);
  int egrid = (EDGES + 255) / 256;        // 3125
  int sgridA = (NB3 + 255) / 256;         // 587
  hipLaunchKernelGGL(hist_kernel, dim3(egrid), dim3(256), 0, stream, ei, attr, cursor, EDGES);
  hipLaunchKernelGGL(scan_a_kernel, dim3(sgridA), dim3(256), 0, stream, cursor, rowptr, blocksums, NB3);
  hipLaunchKernelGGL(scan_b_kernel, dim3(1), dim3(256), 0, stream, blocksums, sgridA);
  hipLaunchKernelGGL(scan_c_kernel, dim3(sgridA), dim3(256), 0, stream, rowptr, cursor, blocksums, NB3);
  hipLaunchKernelGGL(fill_kernel, dim3(egrid), dim3(256), 0, stream, ei, attr, cursor, csr_src, EDGES);

  int ggrid = (NODES + 63) / 64;          // 782
  int ngrid = (NODES + 7) / 8;            // 6250
  int rgrid = (int)(ND / 4 / 256);        // 6250

  for (int t = 0; t < 3; ++t) {
    const float* xt = xsr[t];
    hipLaunchKernelGGL(gemm_kernel, dim3(ggrid), dim3(256), 0, stream,
                       xt, WT + (long)t * 16384, bs + t * 128, eps + t, oac, NODES, 0);
    for (int k = 1; k <= t + 1; ++k) {
      const float* xsrc = xsr[t - (k - 1)];  // delay = k-1 (NU=1)
      hipLaunchKernelGGL(gather_kernel, dim3(ngrid), dim3(256), 0, stream,
                         xsrc, rowptr, csr_src, k - 1, agg);
      hipLaunchKernelGGL(gemm_kernel, dim3(ggrid), dim3(256), 0, stream,
                         agg, WT + (long)(3 + t * 3 + (k - 1)) * 16384,
                         bk + (t * 3 + (k - 1)) * 128, (const float*)nullptr,
                         oac, NODES, 1);
    }
    hipLaunchKernelGGL(residual_kernel, dim3(rgrid), dim3(256), 0, stream,
                       (const float4*)xt, (const float4*)oac, (float4*)xsw[t + 1], ND / 4);
  }
}

// Round 3
// 546.581 us; speedup vs baseline: 5.7982x; 1.2197x over previous
//
#include <hip/hip_runtime.h>
#include <hip/hip_bf16.h>

// DRew-GIN: N=50000 nodes, E=800000 edges, D=128, L=3, NU=1.
// R3: dst-major CSR (key = d*3 + (k-1)), XCD-partitioned fill,
//     one fused kernel per layer (gather->MFMA->residual, no agg/oac).

#define NODES 50000
#define EDGES 800000
#define DIM   128
#define ND    ((long)NODES * DIM)
#define NB3   (3 * NODES)          // buckets: d*3 + (k-1)
#define NPART 8
#define PSIZE (NODES / NPART)      // 6250

typedef __attribute__((ext_vector_type(8))) short  bf16x8;
typedef __attribute__((ext_vector_type(4))) float  f32x4;

#define LDS_STRIDE 136   // 128 + 8 bf16 pad (272B rows): 2-way bank alias only

// ---------------------------------------------------------------------------
// Convert Ws (3) + Wk (9) f32 [k][n] -> bf16 transposed [n][k].
__global__ __launch_bounds__(256) void convw_kernel(
    const float* __restrict__ Ws, const float* __restrict__ Wk,
    __hip_bfloat16* __restrict__ WT) {
  int m = blockIdx.x;  // 0..11
  const float* src = (m < 3) ? (Ws + (long)m * 16384) : (Wk + (long)(m - 3) * 16384);
  __hip_bfloat16* dst = WT + (long)m * 16384;
  for (int idx = threadIdx.x; idx < 16384; idx += 256) {
    int k = idx >> 7, n = idx & 127;
    dst[n * 128 + k] = __float2bfloat16(src[idx]);
  }
}

// ---------------------------------------------------------------------------
// CSR build phase 1: histogram counts[d*3 + (attr-1)].
__global__ __launch_bounds__(256) void hist_kernel(
    const int* __restrict__ ei, const int* __restrict__ attr,
    int* __restrict__ counts, int E) {
  int e = blockIdx.x * 256 + threadIdx.x;
  if (e >= E) return;
  int km1 = attr[e] - 1;
  int d = ei[E + e];
  atomicAdd(&counts[d * 3 + km1], 1);
}

// Phase 2a: per-256-chunk exclusive scan; chunk totals -> blocksums.
__global__ __launch_bounds__(256) void scan_a_kernel(
    const int* __restrict__ counts, int* __restrict__ partial,
    int* __restrict__ blocksums, int n) {
  __shared__ int tmp[256];
  int gid = blockIdx.x * 256 + threadIdx.x;
  int v = (gid < n) ? counts[gid] : 0;
  tmp[threadIdx.x] = v;
  __syncthreads();
  for (int off = 1; off < 256; off <<= 1) {
    int t = (threadIdx.x >= off) ? tmp[threadIdx.x - off] : 0;
    __syncthreads();
    tmp[threadIdx.x] += t;
    __syncthreads();
  }
  if (gid < n) partial[gid] = tmp[threadIdx.x] - v;
  if (threadIdx.x == 255) blocksums[blockIdx.x] = tmp[255];
}

// Phase 2b: single-block exclusive scan of blocksums.
__global__ __launch_bounds__(256) void scan_b_kernel(int* __restrict__ bs, int nb) {
  __shared__ int tmp[256];
  __shared__ int carry;
  if (threadIdx.x == 0) carry = 0;
  __syncthreads();
  for (int base = 0; base < nb; base += 256) {
    int gid = base + threadIdx.x;
    int v = (gid < nb) ? bs[gid] : 0;
    tmp[threadIdx.x] = v;
    __syncthreads();
    for (int off = 1; off < 256; off <<= 1) {
      int t = (threadIdx.x >= off) ? tmp[threadIdx.x - off] : 0;
      __syncthreads();
      tmp[threadIdx.x] += t;
      __syncthreads();
    }
    if (gid < nb) bs[gid] = tmp[threadIdx.x] - v + carry;
    __syncthreads();
    if (threadIdx.x == 0) carry += tmp[255];
    __syncthreads();
  }
}

// Phase 2c: combine; rowptr = cursor = global exclusive scan; rowptr[n] = E.
__global__ __launch_bounds__(256) void scan_c_kernel(
    int* __restrict__ rowptr, int* __restrict__ cursor,
    const int* __restrict__ bs, int n) {
  int gid = blockIdx.x * 256 + threadIdx.x;
  if (gid >= n) return;
  int cnt = cursor[gid];
  int val = rowptr[gid] + bs[blockIdx.x];
  rowptr[gid] = val;
  cursor[gid] = val;
  if (gid == n - 1) rowptr[n] = val + cnt;
}

// Phase 3: XCD-partitioned fill. p = blockIdx&7 handles dst in [p*6250,(p+1)*6250);
// all writes to a csr line then come from (heuristically) one XCD -> L2-coalesced.
__global__ __launch_bounds__(256) void fill_kernel(
    const int* __restrict__ ei, const int* __restrict__ attr,
    int* __restrict__ cursor, int* __restrict__ csr_src, int E) {
  int p = blockIdx.x & (NPART - 1);
  int chunk = blockIdx.x >> 3;
  int e = chunk * 256 + threadIdx.x;
  if (e >= E) return;
  int d = ei[E + e];
  int lo = p * PSIZE;
  if (d < lo || d >= lo + PSIZE) return;
  int km1 = attr[e] - 1;
  int s = ei[e];
  int pos = atomicAdd(&cursor[d * 3 + km1], 1);
  csr_src[pos] = s;
}

// ---------------------------------------------------------------------------
// Fused layer: xn = xt + relu( (1+eps)*relu(xt@Ws+bs) + sum_k relu(gather_k@Wk+bk) )
__global__ __launch_bounds__(256, 3) void layer_kernel(
    const float* __restrict__ xt,
    const float* __restrict__ xsA,   // xsrc for km1=0 (== xt)
    const float* __restrict__ xsB,   // xsrc for km1=1
    const float* __restrict__ xsC,   // xsrc for km1=2
    const __hip_bfloat16* __restrict__ WT,
    const float* __restrict__ bs_t,  // bs + t*128
    const float* __restrict__ bk_t,  // bk + t*3*128
    const float* __restrict__ epsp,  // eps + t
    const int* __restrict__ rowptr,
    const int* __restrict__ csr,
    float* __restrict__ xn,
    int t) {
  __shared__ __hip_bfloat16 b_lds[128 * LDS_STRIDE];  // 34816 B
  __shared__ __hip_bfloat16 a_lds[64 * LDS_STRIDE];   // 17408 B

  int tid = threadIdx.x;
  long row0 = (long)blockIdx.x * 64;
  int wave = tid >> 6, lane = tid & 63;
  int l15 = lane & 15, q = lane >> 4;

  // ---- stage Ws[t] -> b_lds ----
  {
    const float4* bsrc = (const float4*)(WT + (long)t * 16384);
#pragma unroll
    for (int i = 0; i < 8; ++i) {
      int idx = tid + 256 * i;
      int n = idx >> 4, k8 = idx & 15;
      float4 v = bsrc[idx];
      *(float4*)(b_lds + n * LDS_STRIDE + k8 * 8) = v;
    }
  }
  // ---- stage xt tile -> a_lds (f32 -> bf16) ----
  {
#pragma unroll
    for (int i = 0; i < 8; ++i) {
      int c = tid + 256 * i;
      int r = c >> 5, c4 = c & 31;
      long grow = row0 + r;
      float4 v = make_float4(0.f, 0.f, 0.f, 0.f);
      if (grow < NODES) v = *(const float4*)(xt + grow * DIM + c4 * 4);
      union { __hip_bfloat16 h[4]; uint2 u; } pk;
      pk.h[0] = __float2bfloat16(v.x); pk.h[1] = __float2bfloat16(v.y);
      pk.h[2] = __float2bfloat16(v.z); pk.h[3] = __float2bfloat16(v.w);
      *(uint2*)(a_lds + r * LDS_STRIDE + c4 * 4) = pk.u;
    }
  }
  __syncthreads();

  f32x4 out[8];
  {
    f32x4 acc[8] = {};
    for (int k0 = 0; k0 < 128; k0 += 32) {
      bf16x8 af = *(const bf16x8*)(a_lds + (wave * 16 + l15) * LDS_STRIDE + k0 + 8 * q);
#pragma unroll
      for (int j = 0; j < 8; ++j) {
        bf16x8 bfr = *(const bf16x8*)(b_lds + (16 * j + l15) * LDS_STRIDE + k0 + 8 * q);
        acc[j] = __builtin_amdgcn_mfma_f32_16x16x32_bf16(af, bfr, acc[j], 0, 0, 0);
      }
    }
    float sc = 1.0f + *epsp;
#pragma unroll
    for (int j = 0; j < 8; ++j) {
      float b = bs_t[16 * j + l15];
#pragma unroll
      for (int r = 0; r < 4; ++r) out[j][r] = sc * fmaxf(acc[j][r] + b, 0.f);
    }
  }

  const float* xsrcs[3] = {xsA, xsB, xsC};
  for (int km1 = 0; km1 <= t; ++km1) {
    __syncthreads();   // previous MFMA done reading a_lds/b_lds
    // stage Wk[t][km1] -> b_lds
    {
      const float4* bq = (const float4*)(WT + (long)(3 + t * 3 + km1) * 16384);
#pragma unroll
      for (int i = 0; i < 8; ++i) {
        int idx = tid + 256 * i;
        int n = idx >> 4, k8 = idx & 15;
        float4 v = bq[idx];
        *(float4*)(b_lds + n * LDS_STRIDE + k8 * 8) = v;
      }
    }
    // gather segment-sums -> a_lds (bf16). 8 groups of 32 lanes, 8 rows each.
    {
      const float* xsrc = xsrcs[km1];
      int g = tid >> 5, lane32 = tid & 31;
      for (int rr = 0; rr < 8; ++rr) {
        int row = g * 8 + rr;
        long d = row0 + row;
        float4 a = make_float4(0.f, 0.f, 0.f, 0.f);
        if (d < NODES) {
          long bno = d * 3 + km1;
          int beg = rowptr[bno], end = rowptr[bno + 1];
          int i = beg;
          for (; i + 1 < end; i += 2) {
            int s0 = csr[i], s1 = csr[i + 1];
            float4 v0 = *(const float4*)(xsrc + (long)s0 * DIM + lane32 * 4);
            float4 v1 = *(const float4*)(xsrc + (long)s1 * DIM + lane32 * 4);
            a.x += v0.x + v1.x; a.y += v0.y + v1.y;
            a.z += v0.z + v1.z; a.w += v0.w + v1.w;
          }
          if (i < end) {
            int s0 = csr[i];
            float4 v0 = *(const float4*)(xsrc + (long)s0 * DIM + lane32 * 4);
            a.x += v0.x; a.y += v0.y; a.z += v0.z; a.w += v0.w;
          }
        }
        union { __hip_bfloat16 h[4]; uint2 u; } pk;
        pk.h[0] = __float2bfloat16(a.x); pk.h[1] = __float2bfloat16(a.y);
        pk.h[2] = __float2bfloat16(a.z); pk.h[3] = __float2bfloat16(a.w);
        *(uint2*)(a_lds + row * LDS_STRIDE + lane32 * 4) = pk.u;
      }
    }
    __syncthreads();
    f32x4 acc[8] = {};
    for (int k0 = 0; k0 < 128; k0 += 32) {
      bf16x8 af = *(const bf16x8*)(a_lds + (wave * 16 + l15) * LDS_STRIDE + k0 + 8 * q);
#pragma unroll
      for (int j = 0; j < 8; ++j) {
        bf16x8 bfr = *(const bf16x8*)(b_lds + (16 * j + l15) * LDS_STRIDE + k0 + 8 * q);
        acc[j] = __builtin_amdgcn_mfma_f32_16x16x32_bf16(af, bfr, acc[j], 0, 0, 0);
      }
    }
    const float* bb = bk_t + km1 * 128;
#pragma unroll
    for (int j = 0; j < 8; ++j) {
      float b = bb[16 * j + l15];
#pragma unroll
      for (int r = 0; r < 4; ++r) out[j][r] += fmaxf(acc[j][r] + b, 0.f);
    }
  }

  // ---- epilogue: xn = xt + relu(out) ----
  long rbase = row0 + wave * 16 + q * 4;
#pragma unroll
  for (int j = 0; j < 8; ++j) {
    int col = 16 * j + l15;
#pragma unroll
    for (int r = 0; r < 4; ++r) {
      long grow = rbase + r;
      if (grow < NODES) {
        xn[grow * DIM + col] = xt[grow * DIM + col] + fmaxf(out[j][r], 0.f);
      }
    }
  }
}

// ---------------------------------------------------------------------------
extern "C" void kernel_launch(void* const* d_in, const int* in_sizes, int n_in,
                              void* d_out, int out_size, void* d_ws, size_t ws_size,
                              hipStream_t stream) {
  const float* x    = (const float*)d_in[0];
  const int*   ei   = (const int*)d_in[1];
  const int*   attr = (const int*)d_in[2];
  const float* Ws   = (const float*)d_in[3];
  const float* bs   = (const float*)d_in[4];
  const float* Wk   = (const float*)d_in[5];
  const float* bk   = (const float*)d_in[6];
  const float* eps  = (const float*)d_in[7];
  float* out = (float*)d_out;

  char* ws = (char*)d_ws;
  size_t off = 0;
  auto alloc = [&](size_t bytes) { char* p = ws + off; off += (bytes + 255) & ~(size_t)255; return p; };
  float* xs1 = (float*)alloc(ND * 4);
  float* xs2 = (float*)alloc(ND * 4);
  __hip_bfloat16* WT = (__hip_bfloat16*)alloc(12 * 16384 * 2);
  int* cursor    = (int*)alloc((size_t)NB3 * 4);
  int* rowptr    = (int*)alloc((size_t)(NB3 + 1) * 4);
  int* blocksums = (int*)alloc(1024 * 4);
  int* csr_src   = (int*)alloc((size_t)EDGES * 4);

  // Weight conversion + CSR build.
  hipLaunchKernelGGL(convw_kernel, dim3(12), dim3(256), 0, stream, Ws, Wk, WT);
  hipMemsetAsync(cursor, 0, (size_t)NB3 * 4, stream);
  int egrid  = (EDGES + 255) / 256;   // 3125
  int sgridA = (NB3 + 255) / 256;     // 587
  hipLaunchKernelGGL(hist_kernel, dim3(egrid), dim3(256), 0, stream, ei, attr, cursor, EDGES);
  hipLaunchKernelGGL(scan_a_kernel, dim3(sgridA), dim3(256), 0, stream, cursor, rowptr, blocksums, NB3);
  hipLaunchKernelGGL(scan_b_kernel, dim3(1), dim3(256), 0, stream, blocksums, sgridA);
  hipLaunchKernelGGL(scan_c_kernel, dim3(sgridA), dim3(256), 0, stream, rowptr, cursor, blocksums, NB3);
  hipLaunchKernelGGL(fill_kernel, dim3(egrid * NPART), dim3(256), 0, stream, ei, attr, cursor, csr_src, EDGES);

  int ggrid = (NODES + 63) / 64;      // 782

  // Layer 0: xs1 = layer(x)       sources: km1=0 -> x
  hipLaunchKernelGGL(layer_kernel, dim3(ggrid), dim3(256), 0, stream,
                     x, x, (const float*)nullptr, (const float*)nullptr,
                     WT, bs + 0, bk + 0, eps + 0, rowptr, csr_src, xs1, 0);
  // Layer 1: xs2 = layer(xs1)     sources: km1=0 -> xs1, km1=1 -> x
  hipLaunchKernelGGL(layer_kernel, dim3(ggrid), dim3(256), 0, stream,
                     xs1, xs1, x, (const float*)nullptr,
                     WT, bs + 128, bk + 3 * 128, eps + 1, rowptr, csr_src, xs2, 1);
  // Layer 2: out = layer(xs2)     sources: km1=0 -> xs2, km1=1 -> xs1, km1=2 -> x
  hipLaunchKernelGGL(layer_kernel, dim3(ggrid), dim3(256), 0, stream,
                     xs2, xs2, xs1, x,
                     WT, bs + 256, bk + 6 * 128, eps + 2, rowptr, csr_src, out, 2);
}

// Round 4
// 422.780 us; speedup vs baseline: 7.4960x; 1.2928x over previous
//
#include <hip/hip_runtime.h>
#include <hip/hip_bf16.h>

// DRew-GIN: N=50000, E=800000, D=128, L=3, NU=1.
// R4: bf16 shadow tensors for all gathers (256B rows), 16-lane row gather with
//     shfl-broadcast csr indices, fused per-layer kernel.

#define NODES 50000
#define EDGES 800000
#define DIM   128
#define ND    ((long)NODES * DIM)
#define NB3   (3 * NODES)          // buckets: d*3 + (k-1)
#define NPART 8
#define PSIZE (NODES / NPART)

typedef __attribute__((ext_vector_type(8))) short  bf16x8;
typedef __attribute__((ext_vector_type(4))) float  f32x4;

#define LDS_STRIDE 136   // bf16 elements; 272B rows

// ---------------------------------------------------------------------------
__global__ __launch_bounds__(256) void convw_kernel(
    const float* __restrict__ Ws, const float* __restrict__ Wk,
    __hip_bfloat16* __restrict__ WT) {
  int m = blockIdx.x;  // 0..11
  const float* src = (m < 3) ? (Ws + (long)m * 16384) : (Wk + (long)(m - 3) * 16384);
  __hip_bfloat16* dst = WT + (long)m * 16384;
  for (int idx = threadIdx.x; idx < 16384; idx += 256) {
    int k = idx >> 7, n = idx & 127;
    dst[n * 128 + k] = __float2bfloat16(src[idx]);
  }
}

// f32 -> bf16 copy (x shadow).
__global__ __launch_bounds__(256) void x2b_kernel(
    const float4* __restrict__ xin, uint2* __restrict__ xbo, long n4) {
  long i = (long)blockIdx.x * 256 + threadIdx.x;
  if (i >= n4) return;
  float4 v = xin[i];
  union { __hip_bfloat16 h[4]; uint2 u; } pk;
  pk.h[0] = __float2bfloat16(v.x); pk.h[1] = __float2bfloat16(v.y);
  pk.h[2] = __float2bfloat16(v.z); pk.h[3] = __float2bfloat16(v.w);
  xbo[i] = pk.u;
}

// ---------------------------------------------------------------------------
// CSR build: histogram, 3-phase scan, XCD-partitioned fill.
__global__ __launch_bounds__(256) void hist_kernel(
    const int* __restrict__ ei, const int* __restrict__ attr,
    int* __restrict__ counts, int E) {
  int e = blockIdx.x * 256 + threadIdx.x;
  if (e >= E) return;
  atomicAdd(&counts[ei[E + e] * 3 + (attr[e] - 1)], 1);
}

__global__ __launch_bounds__(256) void scan_a_kernel(
    const int* __restrict__ counts, int* __restrict__ partial,
    int* __restrict__ blocksums, int n) {
  __shared__ int tmp[256];
  int gid = blockIdx.x * 256 + threadIdx.x;
  int v = (gid < n) ? counts[gid] : 0;
  tmp[threadIdx.x] = v;
  __syncthreads();
  for (int off = 1; off < 256; off <<= 1) {
    int t = (threadIdx.x >= off) ? tmp[threadIdx.x - off] : 0;
    __syncthreads();
    tmp[threadIdx.x] += t;
    __syncthreads();
  }
  if (gid < n) partial[gid] = tmp[threadIdx.x] - v;
  if (threadIdx.x == 255) blocksums[blockIdx.x] = tmp[255];
}

__global__ __launch_bounds__(256) void scan_b_kernel(int* __restrict__ bs, int nb) {
  __shared__ int tmp[256];
  __shared__ int carry;
  if (threadIdx.x == 0) carry = 0;
  __syncthreads();
  for (int base = 0; base < nb; base += 256) {
    int gid = base + threadIdx.x;
    int v = (gid < nb) ? bs[gid] : 0;
    tmp[threadIdx.x] = v;
    __syncthreads();
    for (int off = 1; off < 256; off <<= 1) {
      int t = (threadIdx.x >= off) ? tmp[threadIdx.x - off] : 0;
      __syncthreads();
      tmp[threadIdx.x] += t;
      __syncthreads();
    }
    if (gid < nb) bs[gid] = tmp[threadIdx.x] - v + carry;
    __syncthreads();
    if (threadIdx.x == 0) carry += tmp[255];
    __syncthreads();
  }
}

__global__ __launch_bounds__(256) void scan_c_kernel(
    int* __restrict__ rowptr, int* __restrict__ cursor,
    const int* __restrict__ bs, int n) {
  int gid = blockIdx.x * 256 + threadIdx.x;
  if (gid >= n) return;
  int cnt = cursor[gid];
  int val = rowptr[gid] + bs[blockIdx.x];
  rowptr[gid] = val;
  cursor[gid] = val;
  if (gid == n - 1) rowptr[n] = val + cnt;
}

__global__ __launch_bounds__(256) void fill_kernel(
    const int* __restrict__ ei, const int* __restrict__ attr,
    int* __restrict__ cursor, int* __restrict__ csr_src, int E) {
  int p = blockIdx.x & (NPART - 1);
  int chunk = blockIdx.x >> 3;
  int e = chunk * 256 + threadIdx.x;
  if (e >= E) return;
  int d = ei[E + e];
  int lo = p * PSIZE;
  if (d < lo || d >= lo + PSIZE) return;
  int pos = atomicAdd(&cursor[d * 3 + (attr[e] - 1)], 1);
  csr_src[pos] = ei[e];
}

// ---------------------------------------------------------------------------
// Fused layer. Sources for gather are bf16 shadows; residual master in f32.
__global__ __launch_bounds__(256, 3) void layer_kernel(
    const float* __restrict__ xt,               // f32 residual source
    const __hip_bfloat16* __restrict__ xbA,     // bf16 shadow of xt (km1=0 + self-term)
    const __hip_bfloat16* __restrict__ xbB,     // km1=1 source
    const __hip_bfloat16* __restrict__ xbC,     // km1=2 source
    const __hip_bfloat16* __restrict__ WT,
    const float* __restrict__ bs_t,
    const float* __restrict__ bk_t,
    const float* __restrict__ epsp,
    const int* __restrict__ rowptr,
    const int* __restrict__ csr,
    float* __restrict__ xn,                     // f32 out
    __hip_bfloat16* __restrict__ xnb,           // bf16 shadow out
    int t) {
  __shared__ __hip_bfloat16 b_lds[128 * LDS_STRIDE];  // 34816 B
  __shared__ __hip_bfloat16 a_lds[64 * LDS_STRIDE];   // 17408 B

  int tid = threadIdx.x;
  long row0 = (long)blockIdx.x * 64;
  int wave = tid >> 6, lane = tid & 63;
  int l15 = lane & 15, q = lane >> 4;

  // ---- stage Ws[t] -> b_lds ----
  {
    const uint4* bsrc = (const uint4*)(WT + (long)t * 16384);
#pragma unroll
    for (int i = 0; i < 8; ++i) {
      int idx = tid + 256 * i;
      int n = idx >> 4, k8 = idx & 15;
      uint4 v = bsrc[idx];
      *(uint4*)(b_lds + n * LDS_STRIDE + k8 * 8) = v;
    }
  }
  // ---- stage xbA tile -> a_lds (bf16 direct) ----
  {
    const uint4* asrc = (const uint4*)xbA;
#pragma unroll
    for (int i = 0; i < 4; ++i) {
      int idx = tid + 256 * i;               // 0..1023
      int r = idx >> 4, c8 = idx & 15;
      long grow = row0 + r;
      uint4 v = make_uint4(0u, 0u, 0u, 0u);
      if (grow < NODES) v = asrc[grow * 16 + c8];
      *(uint4*)(a_lds + r * LDS_STRIDE + c8 * 8) = v;
    }
  }
  __syncthreads();

  f32x4 out[8];
  {
    f32x4 acc[8] = {};
    for (int k0 = 0; k0 < 128; k0 += 32) {
      bf16x8 af = *(const bf16x8*)(a_lds + (wave * 16 + l15) * LDS_STRIDE + k0 + 8 * q);
#pragma unroll
      for (int j = 0; j < 8; ++j) {
        bf16x8 bfr = *(const bf16x8*)(b_lds + (16 * j + l15) * LDS_STRIDE + k0 + 8 * q);
        acc[j] = __builtin_amdgcn_mfma_f32_16x16x32_bf16(af, bfr, acc[j], 0, 0, 0);
      }
    }
    float sc = 1.0f + *epsp;
#pragma unroll
    for (int j = 0; j < 8; ++j) {
      float b = bs_t[16 * j + l15];
#pragma unroll
      for (int r = 0; r < 4; ++r) out[j][r] = sc * fmaxf(acc[j][r] + b, 0.f);
    }
  }

  const __hip_bfloat16* xbs[3] = {xbA, xbB, xbC};
  for (int km1 = 0; km1 <= t; ++km1) {
    __syncthreads();
    // stage Wk[t][km1] -> b_lds
    {
      const uint4* bq = (const uint4*)(WT + (long)(3 + t * 3 + km1) * 16384);
#pragma unroll
      for (int i = 0; i < 8; ++i) {
        int idx = tid + 256 * i;
        int n = idx >> 4, k8 = idx & 15;
        uint4 v = bq[idx];
        *(uint4*)(b_lds + n * LDS_STRIDE + k8 * 8) = v;
      }
    }
    // gather bf16 rows -> a_lds. 16 lanes/row, 16 groups, 4 rows each.
    {
      const __hip_bfloat16* xb = xbs[km1];
      int group = tid >> 4, lane16 = tid & 15;
      for (int rr = 0; rr < 4; ++rr) {
        int row = group * 4 + rr;
        long d = row0 + row;
        float a0 = 0.f, a1 = 0.f, a2 = 0.f, a3 = 0.f,
              a4 = 0.f, a5 = 0.f, a6 = 0.f, a7 = 0.f;
        if (d < NODES) {
          long bno = d * 3 + km1;
          int beg = rowptr[bno], end = rowptr[bno + 1];
          for (int base = beg; base < end; base += 16) {
            int idx = base + lane16;
            int sl = (idx < end) ? csr[idx] : 0;
            int cnt = end - base; if (cnt > 16) cnt = 16;
            int j = 0;
            for (; j + 1 < cnt; j += 2) {
              int s0 = __shfl(sl, j, 16);
              int s1 = __shfl(sl, j + 1, 16);
              uint4 v0 = *(const uint4*)(xb + (long)s0 * DIM + lane16 * 8);
              uint4 v1 = *(const uint4*)(xb + (long)s1 * DIM + lane16 * 8);
              a0 += __uint_as_float(v0.x << 16) + __uint_as_float(v1.x << 16);
              a1 += __uint_as_float(v0.x & 0xffff0000u) + __uint_as_float(v1.x & 0xffff0000u);
              a2 += __uint_as_float(v0.y << 16) + __uint_as_float(v1.y << 16);
              a3 += __uint_as_float(v0.y & 0xffff0000u) + __uint_as_float(v1.y & 0xffff0000u);
              a4 += __uint_as_float(v0.z << 16) + __uint_as_float(v1.z << 16);
              a5 += __uint_as_float(v0.z & 0xffff0000u) + __uint_as_float(v1.z & 0xffff0000u);
              a6 += __uint_as_float(v0.w << 16) + __uint_as_float(v1.w << 16);
              a7 += __uint_as_float(v0.w & 0xffff0000u) + __uint_as_float(v1.w & 0xffff0000u);
            }
            if (j < cnt) {
              int s0 = __shfl(sl, j, 16);
              uint4 v0 = *(const uint4*)(xb + (long)s0 * DIM + lane16 * 8);
              a0 += __uint_as_float(v0.x << 16);
              a1 += __uint_as_float(v0.x & 0xffff0000u);
              a2 += __uint_as_float(v0.y << 16);
              a3 += __uint_as_float(v0.y & 0xffff0000u);
              a4 += __uint_as_float(v0.z << 16);
              a5 += __uint_as_float(v0.z & 0xffff0000u);
              a6 += __uint_as_float(v0.w << 16);
              a7 += __uint_as_float(v0.w & 0xffff0000u);
            }
          }
        }
        union { __hip_bfloat16 h[8]; uint4 u; } pk;
        pk.h[0] = __float2bfloat16(a0); pk.h[1] = __float2bfloat16(a1);
        pk.h[2] = __float2bfloat16(a2); pk.h[3] = __float2bfloat16(a3);
        pk.h[4] = __float2bfloat16(a4); pk.h[5] = __float2bfloat16(a5);
        pk.h[6] = __float2bfloat16(a6); pk.h[7] = __float2bfloat16(a7);
        *(uint4*)(a_lds + row * LDS_STRIDE + lane16 * 8) = pk.u;
      }
    }
    __syncthreads();
    f32x4 acc[8] = {};
    for (int k0 = 0; k0 < 128; k0 += 32) {
      bf16x8 af = *(const bf16x8*)(a_lds + (wave * 16 + l15) * LDS_STRIDE + k0 + 8 * q);
#pragma unroll
      for (int j = 0; j < 8; ++j) {
        bf16x8 bfr = *(const bf16x8*)(b_lds + (16 * j + l15) * LDS_STRIDE + k0 + 8 * q);
        acc[j] = __builtin_amdgcn_mfma_f32_16x16x32_bf16(af, bfr, acc[j], 0, 0, 0);
      }
    }
    const float* bb = bk_t + km1 * 128;
#pragma unroll
    for (int j = 0; j < 8; ++j) {
      float b = bb[16 * j + l15];
#pragma unroll
      for (int r = 0; r < 4; ++r) out[j][r] += fmaxf(acc[j][r] + b, 0.f);
    }
  }

  // ---- epilogue: xn = xt + relu(out); xnb = bf16(xn) ----
  long rbase = row0 + wave * 16 + q * 4;
#pragma unroll
  for (int j = 0; j < 8; ++j) {
    int col = 16 * j + l15;
#pragma unroll
    for (int r = 0; r < 4; ++r) {
      long grow = rbase + r;
      if (grow < NODES) {
        float v = xt[grow * DIM + col] + fmaxf(out[j][r], 0.f);
        xn[grow * DIM + col] = v;
        xnb[grow * DIM + col] = __float2bfloat16(v);
      }
    }
  }
}

// ---------------------------------------------------------------------------
extern "C" void kernel_launch(void* const* d_in, const int* in_sizes, int n_in,
                              void* d_out, int out_size, void* d_ws, size_t ws_size,
                              hipStream_t stream) {
  const float* x    = (const float*)d_in[0];
  const int*   ei   = (const int*)d_in[1];
  const int*   attr = (const int*)d_in[2];
  const float* Ws   = (const float*)d_in[3];
  const float* bs   = (const float*)d_in[4];
  const float* Wk   = (const float*)d_in[5];
  const float* bk   = (const float*)d_in[6];
  const float* eps  = (const float*)d_in[7];
  float* out = (float*)d_out;

  char* ws = (char*)d_ws;
  size_t off = 0;
  auto alloc = [&](size_t bytes) { char* p = ws + off; off += (bytes + 255) & ~(size_t)255; return p; };
  float* xs1 = (float*)alloc(ND * 4);
  float* xs2 = (float*)alloc(ND * 4);
  __hip_bfloat16* xb0 = (__hip_bfloat16*)alloc(ND * 2);   // bf16(x)
  __hip_bfloat16* xb1 = (__hip_bfloat16*)alloc(ND * 2);   // bf16(xs1)
  __hip_bfloat16* xb2 = (__hip_bfloat16*)alloc(ND * 2);   // bf16(xs2)
  __hip_bfloat16* xb3 = (__hip_bfloat16*)alloc(ND * 2);   // scratch (final layer shadow)
  __hip_bfloat16* WT  = (__hip_bfloat16*)alloc(12 * 16384 * 2);
  int* cursor    = (int*)alloc((size_t)NB3 * 4);
  int* rowptr    = (int*)alloc((size_t)(NB3 + 1) * 4);
  int* blocksums = (int*)alloc(1024 * 4);
  int* csr_src   = (int*)alloc((size_t)EDGES * 4);

  hipLaunchKernelGGL(convw_kernel, dim3(12), dim3(256), 0, stream, Ws, Wk, WT);
  hipLaunchKernelGGL(x2b_kernel, dim3((int)(ND / 4 / 256)), dim3(256), 0, stream,
                     (const float4*)x, (uint2*)xb0, ND / 4);
  hipMemsetAsync(cursor, 0, (size_t)NB3 * 4, stream);
  int egrid  = (EDGES + 255) / 256;
  int sgridA = (NB3 + 255) / 256;
  hipLaunchKernelGGL(hist_kernel, dim3(egrid), dim3(256), 0, stream, ei, attr, cursor, EDGES);
  hipLaunchKernelGGL(scan_a_kernel, dim3(sgridA), dim3(256), 0, stream, cursor, rowptr, blocksums, NB3);
  hipLaunchKernelGGL(scan_b_kernel, dim3(1), dim3(256), 0, stream, blocksums, sgridA);
  hipLaunchKernelGGL(scan_c_kernel, dim3(sgridA), dim3(256), 0, stream, rowptr, cursor, blocksums, NB3);
  hipLaunchKernelGGL(fill_kernel, dim3(egrid * NPART), dim3(256), 0, stream, ei, attr, cursor, csr_src, EDGES);

  int ggrid = (NODES + 63) / 64;

  // Layer 0
  hipLaunchKernelGGL(layer_kernel, dim3(ggrid), dim3(256), 0, stream,
                     x, xb0, (const __hip_bfloat16*)nullptr, (const __hip_bfloat16*)nullptr,
                     WT, bs + 0, bk + 0, eps + 0, rowptr, csr_src, xs1, xb1, 0);
  // Layer 1
  hipLaunchKernelGGL(layer_kernel, dim3(ggrid), dim3(256), 0, stream,
                     xs1, xb1, xb0, (const __hip_bfloat16*)nullptr,
                     WT, bs + 128, bk + 3 * 128, eps + 1, rowptr, csr_src, xs2, xb2, 1);
  // Layer 2
  hipLaunchKernelGGL(layer_kernel, dim3(ggrid), dim3(256), 0, stream,
                     xs2, xb2, xb1, xb0,
                     WT, bs + 256, bk + 6 * 128, eps + 2, rowptr, csr_src, out, xb3, 2);
}